// Round 11
// baseline (347.191 us; speedup 1.0000x reference)
//
#include <hip/hip_runtime.h>
#include <hip/hip_fp16.h>

#define NN 100000
#define HD 64
#define NB ((NN + 255) >> 8)   // 391 dst-buckets of 256 nodes
#define P1_CHUNK 8192

// k1: per-chunk LDS histogram of dst>>8 -> global bucket counts
__global__ __launch_bounds__(256) void hist_kernel(const int* __restrict__ dst,
                                                   int* __restrict__ bcnt, int E) {
    __shared__ int hist[NB];
    int t = threadIdx.x;
    int e0 = blockIdx.x * P1_CHUNK;
    int count = min(P1_CHUNK, E - e0);
    for (int b = t; b < NB; b += 256) hist[b] = 0;
    __syncthreads();
    for (int i = t; i < count; i += 256) atomicAdd(&hist[dst[e0 + i] >> 8], 1);
    __syncthreads();
    for (int b = t; b < NB; b += 256) {
        int c = hist[b];
        if (c) atomicAdd(&bcnt[b], c);
    }
}

// k2: single block scan of NB bucket counts -> boff (exclusive), bcur copy
__global__ void bscan_kernel(const int* __restrict__ bcnt, int* __restrict__ boff,
                             int* __restrict__ bcur, int* __restrict__ row_ptr,
                             int E, int n) {
    __shared__ int sm[512];
    int t = threadIdx.x;
    int v = (t < NB) ? bcnt[t] : 0;
    sm[t] = v;
    __syncthreads();
    for (int off = 1; off < 512; off <<= 1) {
        int u = (t >= off) ? sm[t - off] : 0;
        __syncthreads();
        sm[t] += u;
        __syncthreads();
    }
    if (t < NB) {
        boff[t] = sm[t] - v;
        bcur[t] = sm[t] - v;
    }
    if (t == 0) {
        boff[NB] = E;
        row_ptr[n] = E;
    }
}

// k3: chunked bucket scatter — LDS hist, one global atomic per (block,bucket), LDS cursors
__global__ __launch_bounds__(256) void p1_kernel(const int* __restrict__ src,
                                                 const int* __restrict__ dst,
                                                 int* __restrict__ bcur,
                                                 int2* __restrict__ ebuf, int E) {
    __shared__ int hist[NB];
    __shared__ int cur[NB];
    int t = threadIdx.x;
    int e0 = blockIdx.x * P1_CHUNK;
    int count = min(P1_CHUNK, E - e0);
    for (int b = t; b < NB; b += 256) hist[b] = 0;
    __syncthreads();
    for (int i = t; i < count; i += 256) atomicAdd(&hist[dst[e0 + i] >> 8], 1);
    __syncthreads();
    for (int b = t; b < NB; b += 256) {
        int c = hist[b];
        cur[b] = c ? atomicAdd(&bcur[b], c) : 0;
    }
    __syncthreads();
    for (int i = t; i < count; i += 256) {
        int d = dst[e0 + i], s = src[e0 + i];
        int pos = atomicAdd(&cur[d >> 8], 1);
        ebuf[pos] = make_int2(d, s);
    }
}

// k4: one block per bucket — LDS degree count + scan -> row_ptr/dinv, then local scatter
__global__ __launch_bounds__(256) void p2_kernel(const int2* __restrict__ ebuf,
                                                 const int* __restrict__ boff,
                                                 int* __restrict__ row_ptr,
                                                 float* __restrict__ dinv,
                                                 int* __restrict__ csr_src, int n) {
    __shared__ int cnt[256];
    __shared__ int cur[256];
    int b = blockIdx.x;
    int node0 = b << 8;
    int t = threadIdx.x;
    int beg = boff[b], end = boff[b + 1];
    cnt[t] = 0;
    __syncthreads();
    for (int i = beg + t; i < end; i += 256) atomicAdd(&cnt[ebuf[i].x - node0], 1);
    __syncthreads();
    int deg = cnt[t];
    for (int off = 1; off < 256; off <<= 1) {   // inclusive scan
        int v = (t >= off) ? cnt[t - off] : 0;
        __syncthreads();
        cnt[t] += v;
        __syncthreads();
    }
    int excl = cnt[t] - deg;
    int node = node0 + t;
    if (node < n) {
        row_ptr[node] = beg + excl;
        dinv[node] = rsqrtf((float)deg + 1.0f);   // +1 = self loop
    }
    cur[t] = beg + excl;
    __syncthreads();
    for (int i = beg + t; i < end; i += 256) {
        int2 p = ebuf[i];
        int pos = atomicAdd(&cur[p.x - node0], 1);
        csr_src[pos] = p.y;
    }
}

// H(fp16) = (X @ W) * dinv[row] — 64x64 tile/block, 4x4 micro-tile/thread
__global__ __launch_bounds__(256) void matmul64_kernel(const float* __restrict__ X,
                                                       const float* __restrict__ W,
                                                       const float* __restrict__ dinv,
                                                       float2* __restrict__ H, int n) {
    __shared__ float Wl[64 * 64];      // [k][c], float4-aligned
    __shared__ float Xs[64 * 65];      // [r][k], padded
    int tid = threadIdx.x;
    int row0 = blockIdx.x * 64;
    const float4* W4 = (const float4*)W;
    float4* Wl4 = (float4*)Wl;
#pragma unroll
    for (int i = 0; i < 4; ++i) Wl4[tid + 256 * i] = W4[tid + 256 * i];
#pragma unroll
    for (int i = 0; i < 4; ++i) {
        int l = tid + 256 * i;          // 1024 float4s = 64 rows x 16
        int r = l >> 4, k0 = (l & 15) * 4;
        int row = row0 + r;
        float4 xv = (row < n) ? ((const float4*)X)[(size_t)row * 16 + (l & 15)]
                              : make_float4(0.f, 0.f, 0.f, 0.f);
        Xs[r * 65 + k0 + 0] = xv.x;
        Xs[r * 65 + k0 + 1] = xv.y;
        Xs[r * 65 + k0 + 2] = xv.z;
        Xs[r * 65 + k0 + 3] = xv.w;
    }
    __syncthreads();
    int tx = tid & 15, ty = tid >> 4;   // cols c0=4*tx, rows r0=4*ty
    float acc[4][4] = {};
    const float4* Wlr4 = (const float4*)Wl;
#pragma unroll 4
    for (int k = 0; k < 64; ++k) {
        float4 b = Wlr4[k * 16 + tx];
        float a0 = Xs[(ty * 4 + 0) * 65 + k];
        float a1 = Xs[(ty * 4 + 1) * 65 + k];
        float a2 = Xs[(ty * 4 + 2) * 65 + k];
        float a3 = Xs[(ty * 4 + 3) * 65 + k];
        acc[0][0] += a0 * b.x; acc[0][1] += a0 * b.y; acc[0][2] += a0 * b.z; acc[0][3] += a0 * b.w;
        acc[1][0] += a1 * b.x; acc[1][1] += a1 * b.y; acc[1][2] += a1 * b.z; acc[1][3] += a1 * b.w;
        acc[2][0] += a2 * b.x; acc[2][1] += a2 * b.y; acc[2][2] += a2 * b.z; acc[2][3] += a2 * b.w;
        acc[3][0] += a3 * b.x; acc[3][1] += a3 * b.y; acc[3][2] += a3 * b.z; acc[3][3] += a3 * b.w;
    }
#pragma unroll
    for (int j = 0; j < 4; ++j) {
        int row = row0 + ty * 4 + j;
        if (row < n) {
            float dn = dinv[row];
            __half2 p01 = __float22half2_rn(make_float2(acc[j][0] * dn, acc[j][1] * dn));
            __half2 p23 = __float22half2_rn(make_float2(acc[j][2] * dn, acc[j][3] * dn));
            float2 st;
            st.x = *reinterpret_cast<float*>(&p01);
            st.y = *reinterpret_cast<float*>(&p23);
            H[(size_t)row * 16 + tx] = st;
        }
    }
}

#define PK_ACC(RAW) do {                                                     \
    a0 = __hadd2(a0, *reinterpret_cast<__half2*>(&(RAW).x));                 \
    a1 = __hadd2(a1, *reinterpret_cast<__half2*>(&(RAW).y));                 \
    a2 = __hadd2(a2, *reinterpret_cast<__half2*>(&(RAW).z));                 \
    a3 = __hadd2(a3, *reinterpret_cast<__half2*>(&(RAW).w));                 \
} while (0)

// one EIGHTH-wave (8 lanes) per node; lane c8 owns channels 8*c8..8*c8+7 (fp16 x8 = 16B).
// packed fp16 accumulation (v_pk_add_f16); 8 gathers in flight per octet.
__global__ void agg_kernel(const float4* __restrict__ h4, const int* __restrict__ row_ptr,
                           const int* __restrict__ csr_src, const float* __restrict__ dinv,
                           const float* __restrict__ b, const float* __restrict__ xprev,
                           float* __restrict__ xout, float* __restrict__ outp,
                           const float* __restrict__ Wc, const float* __restrict__ bc,
                           int n, int residual, int project) {
    int lane = threadIdx.x & 63;
    int o = lane >> 3, c8 = lane & 7;
    int wid = (blockIdx.x * blockDim.x + threadIdx.x) >> 6;
    int node = wid * 8 + o;
    bool active = node < n;
    int nc = active ? node : 0;
    int beg = row_ptr[nc], end = row_ptr[nc + 1];
    int cnt = end - beg;
    __half2 a0, a1, a2, a3;
    {
        float4 sv = h4[(size_t)nc * 8 + c8];  // self loop (pre-scaled by dinv[src])
        a0 = *reinterpret_cast<__half2*>(&sv.x);
        a1 = *reinterpret_cast<__half2*>(&sv.y);
        a2 = *reinterpret_cast<__half2*>(&sv.z);
        a3 = *reinterpret_cast<__half2*>(&sv.w);
    }
    int base = o * 8;
    for (int k = 0; k < cnt; k += 8) {
        int p = beg + k + c8;
        int sv = (p < end) ? csr_src[p] : 0;
        int m = min(8, cnt - k);
        if (m == 8) {
            int s0 = __shfl(sv, base + 0);
            int s1 = __shfl(sv, base + 1);
            int s2 = __shfl(sv, base + 2);
            int s3 = __shfl(sv, base + 3);
            int s4 = __shfl(sv, base + 4);
            int s5 = __shfl(sv, base + 5);
            int s6 = __shfl(sv, base + 6);
            int s7 = __shfl(sv, base + 7);
            float4 v0 = h4[(size_t)s0 * 8 + c8];
            float4 v1 = h4[(size_t)s1 * 8 + c8];
            float4 v2 = h4[(size_t)s2 * 8 + c8];
            float4 v3 = h4[(size_t)s3 * 8 + c8];
            float4 v4 = h4[(size_t)s4 * 8 + c8];
            float4 v5 = h4[(size_t)s5 * 8 + c8];
            float4 v6 = h4[(size_t)s6 * 8 + c8];
            float4 v7 = h4[(size_t)s7 * 8 + c8];
            PK_ACC(v0); PK_ACC(v1); PK_ACC(v2); PK_ACC(v3);
            PK_ACC(v4); PK_ACC(v5); PK_ACC(v6); PK_ACC(v7);
        } else {
            int i = 0;
            for (; i + 4 <= m; i += 4) {
                int s0 = __shfl(sv, base + i + 0);
                int s1 = __shfl(sv, base + i + 1);
                int s2 = __shfl(sv, base + i + 2);
                int s3 = __shfl(sv, base + i + 3);
                float4 v0 = h4[(size_t)s0 * 8 + c8];
                float4 v1 = h4[(size_t)s1 * 8 + c8];
                float4 v2 = h4[(size_t)s2 * 8 + c8];
                float4 v3 = h4[(size_t)s3 * 8 + c8];
                PK_ACC(v0); PK_ACC(v1); PK_ACC(v2); PK_ACC(v3);
            }
            for (; i < m; ++i) {
                int s = __shfl(sv, base + i);
                float4 hv = h4[(size_t)s * 8 + c8];
                PK_ACC(hv);
            }
        }
    }
    if (active) {
        float dn = dinv[node];
        float2 f0 = __half22float2(a0);
        float2 f1 = __half22float2(a1);
        float2 f2 = __half22float2(a2);
        float2 f3 = __half22float2(a3);
        const float4* b4 = (const float4*)b;
        float4 bb0 = b4[c8 * 2], bb1 = b4[c8 * 2 + 1];
        float4 u, w;
        u.x = f0.x * dn + bb0.x; u.y = f0.y * dn + bb0.y;
        u.z = f1.x * dn + bb0.z; u.w = f1.y * dn + bb0.w;
        w.x = f2.x * dn + bb1.x; w.y = f2.y * dn + bb1.y;
        w.z = f3.x * dn + bb1.z; w.w = f3.y * dn + bb1.w;
        if (residual) {
            const float4* xp4 = (const float4*)xprev;
            float4 r0 = xp4[(size_t)node * 16 + c8 * 2];
            float4 r1 = xp4[(size_t)node * 16 + c8 * 2 + 1];
            u.x += r0.x; u.y += r0.y; u.z += r0.z; u.w += r0.w;
            w.x += r1.x; w.y += r1.y; w.z += r1.z; w.w += r1.w;
        }
        u.x = fmaxf(u.x, 0.f); u.y = fmaxf(u.y, 0.f);
        u.z = fmaxf(u.z, 0.f); u.w = fmaxf(u.w, 0.f);
        w.x = fmaxf(w.x, 0.f); w.y = fmaxf(w.y, 0.f);
        w.z = fmaxf(w.z, 0.f); w.w = fmaxf(w.w, 0.f);
        if (!project) {
            float4* xo4 = (float4*)xout;
            xo4[(size_t)node * 16 + c8 * 2] = u;
            xo4[(size_t)node * 16 + c8 * 2 + 1] = w;
        } else {
            int cb = c8 * 8;
#pragma unroll
            for (int j = 0; j < 3; ++j) {
                float p = u.x * Wc[(cb + 0) * 3 + j] + u.y * Wc[(cb + 1) * 3 + j] +
                          u.z * Wc[(cb + 2) * 3 + j] + u.w * Wc[(cb + 3) * 3 + j] +
                          w.x * Wc[(cb + 4) * 3 + j] + w.y * Wc[(cb + 5) * 3 + j] +
                          w.z * Wc[(cb + 6) * 3 + j] + w.w * Wc[(cb + 7) * 3 + j];
                p += __shfl_down(p, 4, 8);
                p += __shfl_down(p, 2, 8);
                p += __shfl_down(p, 1, 8);
                if (c8 == 0) outp[node * 3 + j] = p + bc[j];
            }
        }
    }
}

extern "C" void kernel_launch(void* const* d_in, const int* in_sizes, int n_in,
                              void* d_out, int out_size, void* d_ws, size_t ws_size,
                              hipStream_t stream) {
    const float* x  = (const float*)d_in[0];
    const int*   ei = (const int*)d_in[1];
    const float* Ws = (const float*)d_in[2];
    const float* bs = (const float*)d_in[3];
    const float* Wc = (const float*)d_in[4];
    const float* bc = (const float*)d_in[5];
    float* out = (float*)d_out;

    int E = in_sizes[1] / 2;
    const int* src = ei;
    const int* dst = ei + E;
    int nchunks = (E + P1_CHUNK - 1) / P1_CHUNK;

    char* wsb = (char*)d_ws;
    size_t off = 0;
    int*   bcnt    = (int*)(wsb + off); off += 512 * 4;
    int*   boff    = (int*)(wsb + off); off += 512 * 4;
    int*   bcur    = (int*)(wsb + off); off += 512 * 4;
    int*   row_ptr = (int*)(wsb + off); off += 100608 * 4;
    float* dinv    = (float*)(wsb + off); off += 100352 * 4;
    int*   csr_src = (int*)(wsb + off); off += ((size_t)E + 256) * 4;
    int2*  ebuf    = (int2*)(wsb + off); off += (size_t)E * 8;           // bucketed pairs
    float2* h      = (float2*)(wsb + off); off += (size_t)NN * HD * 2;   // fp16 h
    float* xa      = (float*)(wsb + off); off += (size_t)NN * HD * 4;
    float* xb      = (float*)(wsb + off); off += (size_t)NN * HD * 4;

    // graph build: bucket counts -> offsets -> bucketed pairs -> per-bucket CSR+deg+dinv
    hipMemsetAsync(bcnt, 0, 512 * sizeof(int), stream);
    hist_kernel<<<nchunks, 256, 0, stream>>>(dst, bcnt, E);
    bscan_kernel<<<1, 512, 0, stream>>>(bcnt, boff, bcur, row_ptr, E, NN);
    p1_kernel<<<nchunks, 256, 0, stream>>>(src, dst, bcur, ebuf, E);
    p2_kernel<<<NB, 256, 0, stream>>>(ebuf, boff, row_ptr, dinv, csr_src, NN);

    // layers (ping-pong xa/xb); layer 3 fuses projection into agg epilogue
    const float* xin = x;
    float* bufs[2] = {xa, xb};
    int agg_blocks = ((NN + 7) / 8 * 64 + 255) / 256;  // 8 nodes per wave
    for (int l = 0; l < 4; ++l) {
        float* xout = bufs[l & 1];
        matmul64_kernel<<<(NN + 63) / 64, 256, 0, stream>>>(
            xin, Ws + (size_t)l * HD * HD, dinv, h, NN);
        agg_kernel<<<agg_blocks, 256, 0, stream>>>(
            (const float4*)h, row_ptr, csr_src, dinv, bs + l * HD, xin, xout,
            out, Wc, bc, NN, l > 0, l == 3);
        xin = xout;
    }
}

// Round 12
// 341.130 us; speedup vs baseline: 1.0178x; 1.0178x over previous
//
#include <hip/hip_runtime.h>
#include <hip/hip_fp16.h>

#define NN 100000
#define HD 64
#define NB ((NN + 255) >> 8)   // 391 dst-buckets of 256 nodes
#define P1_CHUNK 8192

// k1: per-chunk LDS histogram of dst>>8 -> global bucket counts
__global__ __launch_bounds__(256) void hist_kernel(const int* __restrict__ dst,
                                                   int* __restrict__ bcnt, int E) {
    __shared__ int hist[NB];
    int t = threadIdx.x;
    int e0 = blockIdx.x * P1_CHUNK;
    int count = min(P1_CHUNK, E - e0);
    for (int b = t; b < NB; b += 256) hist[b] = 0;
    __syncthreads();
    for (int i = t; i < count; i += 256) atomicAdd(&hist[dst[e0 + i] >> 8], 1);
    __syncthreads();
    for (int b = t; b < NB; b += 256) {
        int c = hist[b];
        if (c) atomicAdd(&bcnt[b], c);
    }
}

// k2: single block scan of NB bucket counts -> boff (exclusive), bcur copy
__global__ void bscan_kernel(const int* __restrict__ bcnt, int* __restrict__ boff,
                             int* __restrict__ bcur, int* __restrict__ row_ptr,
                             int E, int n) {
    __shared__ int sm[512];
    int t = threadIdx.x;
    int v = (t < NB) ? bcnt[t] : 0;
    sm[t] = v;
    __syncthreads();
    for (int off = 1; off < 512; off <<= 1) {
        int u = (t >= off) ? sm[t - off] : 0;
        __syncthreads();
        sm[t] += u;
        __syncthreads();
    }
    if (t < NB) {
        boff[t] = sm[t] - v;
        bcur[t] = sm[t] - v;
    }
    if (t == 0) {
        boff[NB] = E;
        row_ptr[n] = E;
    }
}

// k3: chunked bucket scatter — LDS hist, one global atomic per (block,bucket), LDS cursors.
// ebuf entry packed: (d & 255) << 24 | src   (src < 2^24)
__global__ __launch_bounds__(256) void p1_kernel(const int* __restrict__ src,
                                                 const int* __restrict__ dst,
                                                 int* __restrict__ bcur,
                                                 unsigned* __restrict__ ebuf, int E) {
    __shared__ int hist[NB];
    __shared__ int cur[NB];
    int t = threadIdx.x;
    int e0 = blockIdx.x * P1_CHUNK;
    int count = min(P1_CHUNK, E - e0);
    for (int b = t; b < NB; b += 256) hist[b] = 0;
    __syncthreads();
    for (int i = t; i < count; i += 256) atomicAdd(&hist[dst[e0 + i] >> 8], 1);
    __syncthreads();
    for (int b = t; b < NB; b += 256) {
        int c = hist[b];
        cur[b] = c ? atomicAdd(&bcur[b], c) : 0;
    }
    __syncthreads();
    for (int i = t; i < count; i += 256) {
        int d = dst[e0 + i], s = src[e0 + i];
        int pos = atomicAdd(&cur[d >> 8], 1);
        ebuf[pos] = ((unsigned)(d & 255) << 24) | (unsigned)s;
    }
}

// k4: one block per bucket — LDS degree count + scan -> row_ptr/dinv, then local scatter
__global__ __launch_bounds__(256) void p2_kernel(const unsigned* __restrict__ ebuf,
                                                 const int* __restrict__ boff,
                                                 int* __restrict__ row_ptr,
                                                 float* __restrict__ dinv,
                                                 int* __restrict__ csr_src, int n) {
    __shared__ int cnt[256];
    __shared__ int cur[256];
    int b = blockIdx.x;
    int node0 = b << 8;
    int t = threadIdx.x;
    int beg = boff[b], end = boff[b + 1];
    cnt[t] = 0;
    __syncthreads();
    for (int i = beg + t; i < end; i += 256) atomicAdd(&cnt[ebuf[i] >> 24], 1);
    __syncthreads();
    int deg = cnt[t];
    for (int off = 1; off < 256; off <<= 1) {   // inclusive scan
        int v = (t >= off) ? cnt[t - off] : 0;
        __syncthreads();
        cnt[t] += v;
        __syncthreads();
    }
    int excl = cnt[t] - deg;
    int node = node0 + t;
    if (node < n) {
        row_ptr[node] = beg + excl;
        dinv[node] = rsqrtf((float)deg + 1.0f);   // +1 = self loop
    }
    cur[t] = beg + excl;
    __syncthreads();
    for (int i = beg + t; i < end; i += 256) {
        unsigned p = ebuf[i];
        int pos = atomicAdd(&cur[p >> 24], 1);
        csr_src[pos] = (int)(p & 0xFFFFFFu);
    }
}

// H(fp16) = (X @ W) * dinv[row] — 64x64 tile/block, 4x4 micro-tile/thread.
// X is fp32 (layer 0) or fp16 (layers 1..3), selected by x_is_half.
__global__ __launch_bounds__(256) void matmul64_kernel(const void* __restrict__ Xv,
                                                       int x_is_half,
                                                       const float* __restrict__ W,
                                                       const float* __restrict__ dinv,
                                                       float2* __restrict__ H, int n) {
    __shared__ float Wl[64 * 64];      // [k][c], float4-aligned
    __shared__ float Xs[64 * 65];      // [r][k], padded
    int tid = threadIdx.x;
    int row0 = blockIdx.x * 64;
    const float4* W4 = (const float4*)W;
    float4* Wl4 = (float4*)Wl;
#pragma unroll
    for (int i = 0; i < 4; ++i) Wl4[tid + 256 * i] = W4[tid + 256 * i];
    if (x_is_half) {
        const float4* X4 = (const float4*)Xv;   // 8 fp16 per float4; row = 8 float4s
#pragma unroll
        for (int i = 0; i < 2; ++i) {
            int l = tid + 256 * i;              // 512 float4s = 64 rows x 8
            int r = l >> 3, k0 = (l & 7) * 8;
            int row = row0 + r;
            float4 xv = (row < n) ? X4[(size_t)row * 8 + (l & 7)]
                                  : make_float4(0.f, 0.f, 0.f, 0.f);
            const __half2* hp = (const __half2*)&xv;
#pragma unroll
            for (int j = 0; j < 4; ++j) {
                float2 f = __half22float2(hp[j]);
                Xs[r * 65 + k0 + 2 * j]     = f.x;
                Xs[r * 65 + k0 + 2 * j + 1] = f.y;
            }
        }
    } else {
        const float4* X4 = (const float4*)Xv;
#pragma unroll
        for (int i = 0; i < 4; ++i) {
            int l = tid + 256 * i;              // 1024 float4s = 64 rows x 16
            int r = l >> 4, k0 = (l & 15) * 4;
            int row = row0 + r;
            float4 xv = (row < n) ? X4[(size_t)row * 16 + (l & 15)]
                                  : make_float4(0.f, 0.f, 0.f, 0.f);
            Xs[r * 65 + k0 + 0] = xv.x;
            Xs[r * 65 + k0 + 1] = xv.y;
            Xs[r * 65 + k0 + 2] = xv.z;
            Xs[r * 65 + k0 + 3] = xv.w;
        }
    }
    __syncthreads();
    int tx = tid & 15, ty = tid >> 4;   // cols c0=4*tx, rows r0=4*ty
    float acc[4][4] = {};
    const float4* Wlr4 = (const float4*)Wl;
#pragma unroll 4
    for (int k = 0; k < 64; ++k) {
        float4 b = Wlr4[k * 16 + tx];
        float a0 = Xs[(ty * 4 + 0) * 65 + k];
        float a1 = Xs[(ty * 4 + 1) * 65 + k];
        float a2 = Xs[(ty * 4 + 2) * 65 + k];
        float a3 = Xs[(ty * 4 + 3) * 65 + k];
        acc[0][0] += a0 * b.x; acc[0][1] += a0 * b.y; acc[0][2] += a0 * b.z; acc[0][3] += a0 * b.w;
        acc[1][0] += a1 * b.x; acc[1][1] += a1 * b.y; acc[1][2] += a1 * b.z; acc[1][3] += a1 * b.w;
        acc[2][0] += a2 * b.x; acc[2][1] += a2 * b.y; acc[2][2] += a2 * b.z; acc[2][3] += a2 * b.w;
        acc[3][0] += a3 * b.x; acc[3][1] += a3 * b.y; acc[3][2] += a3 * b.z; acc[3][3] += a3 * b.w;
    }
#pragma unroll
    for (int j = 0; j < 4; ++j) {
        int row = row0 + ty * 4 + j;
        if (row < n) {
            float dn = dinv[row];
            __half2 p01 = __float22half2_rn(make_float2(acc[j][0] * dn, acc[j][1] * dn));
            __half2 p23 = __float22half2_rn(make_float2(acc[j][2] * dn, acc[j][3] * dn));
            float2 st;
            st.x = *reinterpret_cast<float*>(&p01);
            st.y = *reinterpret_cast<float*>(&p23);
            H[(size_t)row * 16 + tx] = st;
        }
    }
}

#define PK_ACC(RAW) do {                                                     \
    a0 = __hadd2(a0, *reinterpret_cast<__half2*>(&(RAW).x));                 \
    a1 = __hadd2(a1, *reinterpret_cast<__half2*>(&(RAW).y));                 \
    a2 = __hadd2(a2, *reinterpret_cast<__half2*>(&(RAW).z));                 \
    a3 = __hadd2(a3, *reinterpret_cast<__half2*>(&(RAW).w));                 \
} while (0)

// one EIGHTH-wave (8 lanes) per node; lane c8 owns channels 8*c8..8*c8+7 (fp16 x8 = 16B).
// packed fp16 accumulation; fp16 activations in/out (xprev/xout); fp32 epilogue.
__global__ void agg_kernel(const float4* __restrict__ h4, const int* __restrict__ row_ptr,
                           const int* __restrict__ csr_src, const float* __restrict__ dinv,
                           const float* __restrict__ b, const float4* __restrict__ xprev,
                           float4* __restrict__ xout, float* __restrict__ outp,
                           const float* __restrict__ Wc, const float* __restrict__ bc,
                           int n, int residual, int project) {
    int lane = threadIdx.x & 63;
    int o = lane >> 3, c8 = lane & 7;
    int wid = (blockIdx.x * blockDim.x + threadIdx.x) >> 6;
    int node = wid * 8 + o;
    bool active = node < n;
    int nc = active ? node : 0;
    int beg = row_ptr[nc], end = row_ptr[nc + 1];
    int cnt = end - beg;
    __half2 a0, a1, a2, a3;
    {
        float4 sv = h4[(size_t)nc * 8 + c8];  // self loop (pre-scaled by dinv[src])
        a0 = *reinterpret_cast<__half2*>(&sv.x);
        a1 = *reinterpret_cast<__half2*>(&sv.y);
        a2 = *reinterpret_cast<__half2*>(&sv.z);
        a3 = *reinterpret_cast<__half2*>(&sv.w);
    }
    int base = o * 8;
    for (int k = 0; k < cnt; k += 8) {
        int p = beg + k + c8;
        int sv = (p < end) ? csr_src[p] : 0;
        int m = min(8, cnt - k);
        if (m == 8) {
            int s0 = __shfl(sv, base + 0);
            int s1 = __shfl(sv, base + 1);
            int s2 = __shfl(sv, base + 2);
            int s3 = __shfl(sv, base + 3);
            int s4 = __shfl(sv, base + 4);
            int s5 = __shfl(sv, base + 5);
            int s6 = __shfl(sv, base + 6);
            int s7 = __shfl(sv, base + 7);
            float4 v0 = h4[(size_t)s0 * 8 + c8];
            float4 v1 = h4[(size_t)s1 * 8 + c8];
            float4 v2 = h4[(size_t)s2 * 8 + c8];
            float4 v3 = h4[(size_t)s3 * 8 + c8];
            float4 v4 = h4[(size_t)s4 * 8 + c8];
            float4 v5 = h4[(size_t)s5 * 8 + c8];
            float4 v6 = h4[(size_t)s6 * 8 + c8];
            float4 v7 = h4[(size_t)s7 * 8 + c8];
            PK_ACC(v0); PK_ACC(v1); PK_ACC(v2); PK_ACC(v3);
            PK_ACC(v4); PK_ACC(v5); PK_ACC(v6); PK_ACC(v7);
        } else {
            int i = 0;
            for (; i + 4 <= m; i += 4) {
                int s0 = __shfl(sv, base + i + 0);
                int s1 = __shfl(sv, base + i + 1);
                int s2 = __shfl(sv, base + i + 2);
                int s3 = __shfl(sv, base + i + 3);
                float4 v0 = h4[(size_t)s0 * 8 + c8];
                float4 v1 = h4[(size_t)s1 * 8 + c8];
                float4 v2 = h4[(size_t)s2 * 8 + c8];
                float4 v3 = h4[(size_t)s3 * 8 + c8];
                PK_ACC(v0); PK_ACC(v1); PK_ACC(v2); PK_ACC(v3);
            }
            for (; i < m; ++i) {
                int s = __shfl(sv, base + i);
                float4 hv = h4[(size_t)s * 8 + c8];
                PK_ACC(hv);
            }
        }
    }
    if (active) {
        float dn = dinv[node];
        float2 f0 = __half22float2(a0);
        float2 f1 = __half22float2(a1);
        float2 f2 = __half22float2(a2);
        float2 f3 = __half22float2(a3);
        const float4* b4 = (const float4*)b;
        float4 bb0 = b4[c8 * 2], bb1 = b4[c8 * 2 + 1];
        float4 u, w;
        u.x = f0.x * dn + bb0.x; u.y = f0.y * dn + bb0.y;
        u.z = f1.x * dn + bb0.z; u.w = f1.y * dn + bb0.w;
        w.x = f2.x * dn + bb1.x; w.y = f2.y * dn + bb1.y;
        w.z = f3.x * dn + bb1.z; w.w = f3.y * dn + bb1.w;
        if (residual) {
            float4 rr = xprev[(size_t)node * 8 + c8];   // 8 fp16
            const __half2* rp = (const __half2*)&rr;
            float2 r0 = __half22float2(rp[0]);
            float2 r1 = __half22float2(rp[1]);
            float2 r2 = __half22float2(rp[2]);
            float2 r3 = __half22float2(rp[3]);
            u.x += r0.x; u.y += r0.y; u.z += r1.x; u.w += r1.y;
            w.x += r2.x; w.y += r2.y; w.z += r3.x; w.w += r3.y;
        }
        u.x = fmaxf(u.x, 0.f); u.y = fmaxf(u.y, 0.f);
        u.z = fmaxf(u.z, 0.f); u.w = fmaxf(u.w, 0.f);
        w.x = fmaxf(w.x, 0.f); w.y = fmaxf(w.y, 0.f);
        w.z = fmaxf(w.z, 0.f); w.w = fmaxf(w.w, 0.f);
        if (!project) {
            __half2 o0 = __float22half2_rn(make_float2(u.x, u.y));
            __half2 o1 = __float22half2_rn(make_float2(u.z, u.w));
            __half2 o2 = __float22half2_rn(make_float2(w.x, w.y));
            __half2 o3 = __float22half2_rn(make_float2(w.z, w.w));
            float4 st;
            st.x = *reinterpret_cast<float*>(&o0);
            st.y = *reinterpret_cast<float*>(&o1);
            st.z = *reinterpret_cast<float*>(&o2);
            st.w = *reinterpret_cast<float*>(&o3);
            xout[(size_t)node * 8 + c8] = st;
        } else {
            int cb = c8 * 8;
#pragma unroll
            for (int j = 0; j < 3; ++j) {
                float p = u.x * Wc[(cb + 0) * 3 + j] + u.y * Wc[(cb + 1) * 3 + j] +
                          u.z * Wc[(cb + 2) * 3 + j] + u.w * Wc[(cb + 3) * 3 + j] +
                          w.x * Wc[(cb + 4) * 3 + j] + w.y * Wc[(cb + 5) * 3 + j] +
                          w.z * Wc[(cb + 6) * 3 + j] + w.w * Wc[(cb + 7) * 3 + j];
                p += __shfl_down(p, 4, 8);
                p += __shfl_down(p, 2, 8);
                p += __shfl_down(p, 1, 8);
                if (c8 == 0) outp[node * 3 + j] = p + bc[j];
            }
        }
    }
}

extern "C" void kernel_launch(void* const* d_in, const int* in_sizes, int n_in,
                              void* d_out, int out_size, void* d_ws, size_t ws_size,
                              hipStream_t stream) {
    const float* x  = (const float*)d_in[0];
    const int*   ei = (const int*)d_in[1];
    const float* Ws = (const float*)d_in[2];
    const float* bs = (const float*)d_in[3];
    const float* Wc = (const float*)d_in[4];
    const float* bc = (const float*)d_in[5];
    float* out = (float*)d_out;

    int E = in_sizes[1] / 2;
    const int* src = ei;
    const int* dst = ei + E;
    int nchunks = (E + P1_CHUNK - 1) / P1_CHUNK;

    char* wsb = (char*)d_ws;
    size_t off = 0;
    int*      bcnt    = (int*)(wsb + off); off += 512 * 4;
    int*      boff    = (int*)(wsb + off); off += 512 * 4;
    int*      bcur    = (int*)(wsb + off); off += 512 * 4;
    int*      row_ptr = (int*)(wsb + off); off += 100608 * 4;
    float*    dinv    = (float*)(wsb + off); off += 100352 * 4;
    int*      csr_src = (int*)(wsb + off); off += ((size_t)E + 256) * 4;
    unsigned* ebuf    = (unsigned*)(wsb + off); off += (size_t)E * 4;     // packed pairs
    float2*   h       = (float2*)(wsb + off); off += (size_t)NN * HD * 2; // fp16 h
    float4*   xa      = (float4*)(wsb + off); off += (size_t)NN * HD * 2; // fp16 acts
    float4*   xb      = (float4*)(wsb + off); off += (size_t)NN * HD * 2;

    // graph build: bucket counts -> offsets -> packed bucketed pairs -> per-bucket CSR+deg+dinv
    hipMemsetAsync(bcnt, 0, 512 * sizeof(int), stream);
    hist_kernel<<<nchunks, 256, 0, stream>>>(dst, bcnt, E);
    bscan_kernel<<<1, 512, 0, stream>>>(bcnt, boff, bcur, row_ptr, E, NN);
    p1_kernel<<<nchunks, 256, 0, stream>>>(src, dst, bcur, ebuf, E);
    p2_kernel<<<NB, 256, 0, stream>>>(ebuf, boff, row_ptr, dinv, csr_src, NN);

    // layers (ping-pong xa/xb fp16); layer 3 fuses projection into agg epilogue
    const void* xin = (const void*)x;
    int xin_half = 0;
    float4* bufs[2] = {xa, xb};
    int agg_blocks = ((NN + 7) / 8 * 64 + 255) / 256;  // 8 nodes per wave
    for (int l = 0; l < 4; ++l) {
        float4* xout = bufs[l & 1];
        matmul64_kernel<<<(NN + 63) / 64, 256, 0, stream>>>(
            xin, xin_half, Ws + (size_t)l * HD * HD, dinv, h, NN);
        agg_kernel<<<agg_blocks, 256, 0, stream>>>(
            (const float4*)h, row_ptr, csr_src, dinv, bs + l * HD,
            (const float4*)xin, xout, out, Wc, bc, NN, l > 0, l == 3);
        xin = (const void*)xout;
        xin_half = 1;
    }
}